// Round 5
// baseline (309.451 us; speedup 1.0000x reference)
//
#include <hip/hip_runtime.h>
#include <hip/hip_bf16.h>

#define B_TOT 16384
#define DIMN  4096
#define EPSF  1e-10f

// ws layout (floats): absamp[16384*8] at 0, blocksum[256*3] at 131072
#define ABS_OFF 0u
#define MET_OFF 131072u

__device__ __forceinline__ void normalize8(float* rr, float* ii) {
  float n2 = 0.f;
#pragma unroll
  for (int q = 0; q < 8; q++) n2 += rr[q] * rr[q] + ii[q] * ii[q];
  float n = sqrtf(n2);
  if (n < EPSF) {
#pragma unroll
    for (int q = 0; q < 8; q++) { rr[q] = 0.f; ii[q] = 0.f; }
    rr[0] = 1.f;
  } else {
    float inv = 1.f / n;
#pragma unroll
    for (int q = 0; q < 8; q++) { rr[q] *= inv; ii[q] *= inv; }
  }
}

// K1: fused enc GEMM + quantum evolve + metrics. ALL f32.
// Grid 256 blocks x 512 threads (8 waves). Block owns 64 rows (lane = row).
// Wave w computes enc features k = {2w, 2w+1} over the full K=4096.
__global__ __launch_bounds__(512) void k_encevolve(
    const float* __restrict__ x, const float* __restrict__ wenc,
    const float* __restrict__ benc, const float* __restrict__ phase,
    const float* __restrict__ disorder, float* __restrict__ absamp,
    float* __restrict__ blocksum) {
  __shared__ float xt[64 * 129];               // x tile (stride 129)
  const int t = threadIdx.x;
  const int l = t & 63;                         // lane = row within block
  const int w = t >> 6;                         // wave id 0..7
  const int r0 = blockIdx.x * 64;

  float acc0 = 0.f, acc1 = 0.f;
  const float* __restrict__ wk0 = wenc + (size_t)(2 * w) * DIMN;  // wave-uniform
  const float* __restrict__ wk1 = wk0 + DIMN;

  for (int c = 0; c < DIMN; c += 128) {
    __syncthreads();                            // tile free from previous compute
    // stage x tile: 64 rows x 128 cols f32, float4 coalesced
#pragma unroll
    for (int j = 0; j < 4; j++) {
      int v = j * 512 + t;                      // 0..2047 float4 slots
      int row = v >> 5;                         // 32 float4 per row
      int fl = (v & 31) << 2;
      float4 xv = *reinterpret_cast<const float4*>(
          x + (size_t)(r0 + row) * DIMN + c + fl);
      float* dst = xt + row * 129 + fl;
      dst[0] = xv.x; dst[1] = xv.y; dst[2] = xv.z; dst[3] = xv.w;
    }
    __syncthreads();
#pragma unroll 8
    for (int i = 0; i < 128; i++) {
      float xv = xt[l * 129 + i];               // stride-129 -> 2/bank (free)
      acc0 = fmaf(xv, wk0[c + i], acc0);        // uniform addr -> L2-cached
      acc1 = fmaf(xv, wk1[c + i], acc1);
    }
  }
  __syncthreads();
  // enc2[row][k] into xt[0..1023]
  xt[l * 16 + 2 * w]     = tanhf(acc0 + benc[2 * w]);
  xt[l * 16 + 2 * w + 1] = tanhf(acc1 + benc[2 * w + 1]);
  __syncthreads();

  if (t < 64) {                                 // wave 0: one row per lane
    const int r = r0 + t;
    float e[16];
#pragma unroll
    for (int k = 0; k < 16; k++) e[k] = xt[t * 16 + k];

    float re[8], im[8];
#pragma unroll
    for (int q = 0; q < 8; q++) {
      float ph = 0.1f * phase[q];
      float cc = cosf(ph), ss = sinf(ph);
      re[q] = e[q] * cc - e[8 + q] * ss + 0.017677669529663688f;  // +0.05/sqrt(8)
      im[q] = e[q] * ss + e[8 + q] * cc;
    }
    normalize8(re, im);

    // Hz diagonal: qubit 0 -> bit2, qubit 1 -> bit1, qubit 2 -> bit0
    float dd0 = disorder[0], dd1 = disorder[1], dd2 = disorder[2];
    float hz[8];
#pragma unroll
    for (int i = 0; i < 8; i++)
      hz[i] = ((i & 4) ? -dd0 : dd0) + ((i & 2) ? -dd1 : dd1) + ((i & 1) ? -dd2 : dd2);

#pragma unroll
    for (int step = 0; step < 2; step++) {
      float tt = 0.02f * (float)r + 0.01f * (float)step;
      float drive = 0.5f + 0.2f * sinf(1.61803398874989485f * tt);
      float nr[8], ni[8];
#pragma unroll
      for (int j = 0; j < 8; j++) {
        float hr = drive * (re[j ^ 1] + re[j ^ 2] + re[j ^ 4]) + hz[j] * re[j];
        float hi = drive * (im[j ^ 1] + im[j ^ 2] + im[j ^ 4]) + hz[j] * im[j];
        nr[j] = re[j] + 1e-4f * hi;             // amps - 1j*1e-4*Ha
        ni[j] = im[j] - 1e-4f * hr;
      }
      normalize8(nr, ni);
#pragma unroll
      for (int j = 0; j < 8; j++) { re[j] = nr[j]; im[j] = ni[j]; }
    }

    float tr = 0.f, s2 = 0.f;
    float ab[8];
#pragma unroll
    for (int q = 0; q < 8; q++) {
      float a2 = re[q] * re[q] + im[q] * im[q];
      tr += a2; s2 += a2 * a2;
      ab[q] = sqrtf(a2);
    }
    *reinterpret_cast<float4*>(absamp + (size_t)r * 8) =
        make_float4(ab[0], ab[1], ab[2], ab[3]);
    *reinterpret_cast<float4*>(absamp + (size_t)r * 8 + 4) =
        make_float4(ab[4], ab[5], ab[6], ab[7]);

    float trp = tr + EPSF;
    float purity = tr * tr / (trp * trp);
    float coh = sqrtf(fmaxf(tr * tr - s2, 0.f)) / trp;
    // rho rank-1: eigvals = [tr/(tr+eps), 0 x7]; clip -> [lam, EPS x7]
    float lam = fminf(fmaxf(tr / trp, EPSF), 1.f);
    float denom = lam + 8.f * EPSF;
    float e1 = lam / denom, er = EPSF / denom;
    float ent = -(e1 * log2f(e1 + EPSF) + 7.f * er * log2f(er + EPSF));

    float sp = purity, sc = coh, sh = ent;
#pragma unroll
    for (int off = 32; off > 0; off >>= 1) {
      sp += __shfl_down(sp, off);
      sc += __shfl_down(sc, off);
      sh += __shfl_down(sh, off);
    }
    if (t == 0) {
      blocksum[blockIdx.x * 3 + 0] = sp;
      blocksum[blockIdx.x * 3 + 1] = sc;
      blocksum[blockIdx.x * 3 + 2] = sh;
    }
  }
}

// K2: out[r][c] = sum_q absamp[r][q]*W_dec[c][q] + b_dec[c]; ALL f32, f32 store
__global__ __launch_bounds__(256) void k_out(const float* __restrict__ absamp,
                                             const float* __restrict__ wdec,
                                             const float* __restrict__ bdec,
                                             float* __restrict__ out) {
  const int t = threadIdx.x;
  const int r0 = blockIdx.x * 64;
  const int c0 = blockIdx.y * 1024 + t * 4;
  float wv[4][8];
#pragma unroll
  for (int j = 0; j < 4; j++) {
    float4 a = *reinterpret_cast<const float4*>(wdec + (size_t)(c0 + j) * 8);
    float4 b = *reinterpret_cast<const float4*>(wdec + (size_t)(c0 + j) * 8 + 4);
    wv[j][0] = a.x; wv[j][1] = a.y; wv[j][2] = a.z; wv[j][3] = a.w;
    wv[j][4] = b.x; wv[j][5] = b.y; wv[j][6] = b.z; wv[j][7] = b.w;
  }
  float4 bd = *reinterpret_cast<const float4*>(bdec + c0);

  __shared__ float as_[512];                    // 64 rows x 8 q
  float2 av = *reinterpret_cast<const float2*>(absamp + (size_t)r0 * 8 + t * 2);
  as_[t * 2] = av.x; as_[t * 2 + 1] = av.y;
  __syncthreads();

  for (int r = 0; r < 64; r++) {
    float o0 = bd.x, o1 = bd.y, o2 = bd.z, o3 = bd.w;
#pragma unroll
    for (int q = 0; q < 8; q++) {
      float aq = as_[r * 8 + q];                // uniform -> broadcast
      o0 = fmaf(aq, wv[0][q], o0);
      o1 = fmaf(aq, wv[1][q], o1);
      o2 = fmaf(aq, wv[2][q], o2);
      o3 = fmaf(aq, wv[3][q], o3);
    }
    *reinterpret_cast<float4*>(out + (size_t)(r0 + r) * DIMN + c0) =
        make_float4(o0, o1, o2, o3);
  }
}

// K3: finalize metric means -> f32 at end of d_out
__global__ void k_final(const float* __restrict__ blocksum,
                        float* __restrict__ out) {
  if (threadIdx.x == 0 && blockIdx.x == 0) {
    float s0 = 0.f, s1 = 0.f, s2 = 0.f;
    for (int b = 0; b < 256; b++) {
      s0 += blocksum[b * 3 + 0];
      s1 += blocksum[b * 3 + 1];
      s2 += blocksum[b * 3 + 2];
    }
    out[(size_t)B_TOT * DIMN + 0] = s0 / 16384.f;
    out[(size_t)B_TOT * DIMN + 1] = s1 / 16384.f;
    out[(size_t)B_TOT * DIMN + 2] = s2 / 16384.f;
  }
}

extern "C" void kernel_launch(void* const* d_in, const int* in_sizes, int n_in,
                              void* d_out, int out_size, void* d_ws, size_t ws_size,
                              hipStream_t stream) {
  // Identify inputs by element count (all distinct) - robust to ordering. All f32.
  const float *x = nullptr, *wenc = nullptr, *benc = nullptr, *phase = nullptr,
              *wdec = nullptr, *bdec = nullptr, *dis = nullptr;
  for (int i = 0; i < n_in; i++) {
    switch (in_sizes[i]) {
      case 67108864: x = (const float*)d_in[i]; break;      // 16384*4096
      case 65536:    wenc = (const float*)d_in[i]; break;   // 16*4096
      case 16:       benc = (const float*)d_in[i]; break;
      case 8:        phase = (const float*)d_in[i]; break;
      case 32768:    wdec = (const float*)d_in[i]; break;   // 4096*8
      case 4096:     bdec = (const float*)d_in[i]; break;
      case 3:        dis = (const float*)d_in[i]; break;
      default: break;
    }
  }

  float* ws = (float*)d_ws;
  float* absamp = ws + ABS_OFF;
  float* bsum   = ws + MET_OFF;
  float* out = (float*)d_out;

  hipLaunchKernelGGL(k_encevolve, dim3(256), dim3(512), 0, stream,
                     x, wenc, benc, phase, dis, absamp, bsum);
  hipLaunchKernelGGL(k_out, dim3(256, 4), dim3(256), 0, stream,
                     absamp, wdec, bdec, out);
  hipLaunchKernelGGL(k_final, dim3(1), dim3(64), 0, stream, bsum, out);
}

// Round 6
// 229.594 us; speedup vs baseline: 1.3478x; 1.3478x over previous
//
#include <hip/hip_runtime.h>

#define B_TOT 16384
#define DIMN  4096
#define EPSF  1e-10f

__device__ __forceinline__ void normalize8(float* rr, float* ii) {
  float n2 = 0.f;
#pragma unroll
  for (int q = 0; q < 8; q++) n2 += rr[q] * rr[q] + ii[q] * ii[q];
  float n = sqrtf(n2);
  if (n < EPSF) {
#pragma unroll
    for (int q = 0; q < 8; q++) { rr[q] = 0.f; ii[q] = 0.f; }
    rr[0] = 1.f;
  } else {
    float inv = 1.f / n;
#pragma unroll
    for (int q = 0; q < 8; q++) { rr[q] *= inv; ii[q] *= inv; }
  }
}

// Fused: enc GEMM (reg-tiled, lane-K-sliced) + reduce + evolve + metrics + decoder out.
// Grid 1024 blocks x 256 threads (4 waves). Block owns 16 rows; wave wv owns rows
// r0 + wv*4 + j (j=0..3) x all 16 features; lane owns a K-slice.
__global__ __launch_bounds__(256) void k_fused(
    const float* __restrict__ x, const float* __restrict__ wenc,
    const float* __restrict__ benc, const float* __restrict__ phase,
    const float* __restrict__ disorder, const float* __restrict__ wdec,
    const float* __restrict__ bdec, float* __restrict__ out,
    float* __restrict__ blocksum) {
  __shared__ float wbuf[8192];                 // 32 KB: W chunk [16][512]; reused as reduce buf
  __shared__ float encL[16 * 17];
  __shared__ float absL[128];
  const int t = threadIdx.x;
  const int l = t & 63;
  const int wv = t >> 6;
  const int r0 = blockIdx.x * 16;

  float acc[4][16];
#pragma unroll
  for (int j = 0; j < 4; j++)
#pragma unroll
    for (int f = 0; f < 16; f++) acc[j][f] = 0.f;

  const float* xb0 = x + (size_t)(r0 + wv * 4 + 0) * DIMN;
  const float* xb1 = x + (size_t)(r0 + wv * 4 + 1) * DIMN;
  const float* xb2 = x + (size_t)(r0 + wv * 4 + 2) * DIMN;
  const float* xb3 = x + (size_t)(r0 + wv * 4 + 3) * DIMN;

  for (int c = 0; c < 8; ++c) {                // K chunks of 512
    __syncthreads();
    // stage W chunk [16][512] -> LDS, coalesced float4
#pragma unroll
    for (int j = 0; j < 8; ++j) {
      int fl = j * 1024 + t * 4;               // dw index in tile
      *reinterpret_cast<float4*>(&wbuf[fl]) = *reinterpret_cast<const float4*>(
          wenc + (size_t)(fl >> 9) * DIMN + c * 512 + (fl & 511));
    }
    __syncthreads();
    const int ka = c * 512 + l * 4;            // lane K-slice A
    const int kb = ka + 256;                   // lane K-slice B
    float4 xa0 = *reinterpret_cast<const float4*>(xb0 + ka);
    float4 xa1 = *reinterpret_cast<const float4*>(xb1 + ka);
    float4 xa2 = *reinterpret_cast<const float4*>(xb2 + ka);
    float4 xa3 = *reinterpret_cast<const float4*>(xb3 + ka);
    float4 xc0 = *reinterpret_cast<const float4*>(xb0 + kb);
    float4 xc1 = *reinterpret_cast<const float4*>(xb1 + kb);
    float4 xc2 = *reinterpret_cast<const float4*>(xb2 + kb);
    float4 xc3 = *reinterpret_cast<const float4*>(xb3 + kb);
#pragma unroll
    for (int f = 0; f < 16; ++f) {
      float4 wa = *reinterpret_cast<const float4*>(&wbuf[f * 512 + l * 4]);
      float4 wb = *reinterpret_cast<const float4*>(&wbuf[f * 512 + 256 + l * 4]);
      acc[0][f] = fmaf(xa0.x, wa.x, fmaf(xa0.y, wa.y, fmaf(xa0.z, wa.z, fmaf(xa0.w, wa.w,
                  fmaf(xc0.x, wb.x, fmaf(xc0.y, wb.y, fmaf(xc0.z, wb.z, fmaf(xc0.w, wb.w, acc[0][f]))))))));
      acc[1][f] = fmaf(xa1.x, wa.x, fmaf(xa1.y, wa.y, fmaf(xa1.z, wa.z, fmaf(xa1.w, wa.w,
                  fmaf(xc1.x, wb.x, fmaf(xc1.y, wb.y, fmaf(xc1.z, wb.z, fmaf(xc1.w, wb.w, acc[1][f]))))))));
      acc[2][f] = fmaf(xa2.x, wa.x, fmaf(xa2.y, wa.y, fmaf(xa2.z, wa.z, fmaf(xa2.w, wa.w,
                  fmaf(xc2.x, wb.x, fmaf(xc2.y, wb.y, fmaf(xc2.z, wb.z, fmaf(xc2.w, wb.w, acc[2][f]))))))));
      acc[3][f] = fmaf(xa3.x, wa.x, fmaf(xa3.y, wa.y, fmaf(xa3.z, wa.z, fmaf(xa3.w, wa.w,
                  fmaf(xc3.x, wb.x, fmaf(xc3.y, wb.y, fmaf(xc3.z, wb.z, fmaf(xc3.w, wb.w, acc[3][f]))))))));
    }
  }

  // Cross-lane reduction via LDS transpose, one wave per round (buf = wbuf reuse).
  for (int wr = 0; wr < 4; ++wr) {
    __syncthreads();
    if (wv == wr) {
#pragma unroll
      for (int o = 0; o < 64; ++o) wbuf[o * 68 + l] = acc[o >> 4][o & 15];
    }
    __syncthreads();
    const int o = t >> 2, s = t & 3;
    float sum = 0.f;
#pragma unroll
    for (int m = 0; m < 4; ++m) {
      float4 v = *reinterpret_cast<const float4*>(&wbuf[o * 68 + s * 16 + m * 4]);
      sum += (v.x + v.y) + (v.z + v.w);
    }
    sum += __shfl_xor(sum, 1);
    sum += __shfl_xor(sum, 2);
    if ((t & 3) == 0) encL[(wr * 4 + (o >> 4)) * 17 + (o & 15)] = sum;
  }
  __syncthreads();

  if (t < 16) {                                // one thread per row: evolve + metrics
    const int r = r0 + t;
    float e[16];
#pragma unroll
    for (int k = 0; k < 16; k++) e[k] = tanhf(encL[t * 17 + k] + benc[k]);

    float re[8], im[8];
#pragma unroll
    for (int q = 0; q < 8; q++) {
      float ph = 0.1f * phase[q];
      float cc = cosf(ph), ss = sinf(ph);
      re[q] = e[q] * cc - e[8 + q] * ss + 0.017677669529663688f;  // +0.05/sqrt(8)
      im[q] = e[q] * ss + e[8 + q] * cc;
    }
    normalize8(re, im);

    float dd0 = disorder[0], dd1 = disorder[1], dd2 = disorder[2];
    float hz[8];
#pragma unroll
    for (int i = 0; i < 8; i++)
      hz[i] = ((i & 4) ? -dd0 : dd0) + ((i & 2) ? -dd1 : dd1) + ((i & 1) ? -dd2 : dd2);

#pragma unroll
    for (int step = 0; step < 2; step++) {
      float tt = 0.02f * (float)r + 0.01f * (float)step;
      float drive = 0.5f + 0.2f * sinf(1.61803398874989485f * tt);
      float nr[8], ni[8];
#pragma unroll
      for (int j = 0; j < 8; j++) {
        float hr = drive * (re[j ^ 1] + re[j ^ 2] + re[j ^ 4]) + hz[j] * re[j];
        float hi = drive * (im[j ^ 1] + im[j ^ 2] + im[j ^ 4]) + hz[j] * im[j];
        nr[j] = re[j] + 1e-4f * hi;            // amps - 1j*1e-4*Ha
        ni[j] = im[j] - 1e-4f * hr;
      }
      normalize8(nr, ni);
#pragma unroll
      for (int j = 0; j < 8; j++) { re[j] = nr[j]; im[j] = ni[j]; }
    }

    float tr = 0.f, s2 = 0.f;
#pragma unroll
    for (int q = 0; q < 8; q++) {
      float a2 = re[q] * re[q] + im[q] * im[q];
      tr += a2; s2 += a2 * a2;
      absL[t * 8 + q] = sqrtf(a2);
    }
    float trp = tr + EPSF;
    float purity = tr * tr / (trp * trp);
    float coh = sqrtf(fmaxf(tr * tr - s2, 0.f)) / trp;
    float lam = fminf(fmaxf(tr / trp, EPSF), 1.f);  // rho rank-1
    float denom = lam + 8.f * EPSF;
    float e1 = lam / denom, er = EPSF / denom;
    float ent = -(e1 * log2f(e1 + EPSF) + 7.f * er * log2f(er + EPSF));

    float sp = purity, sc = coh, sh = ent;
#pragma unroll
    for (int off = 8; off > 0; off >>= 1) {
      sp += __shfl_down(sp, off);
      sc += __shfl_down(sc, off);
      sh += __shfl_down(sh, off);
    }
    if (t == 0) {
      blocksum[blockIdx.x * 3 + 0] = sp;
      blocksum[blockIdx.x * 3 + 1] = sc;
      blocksum[blockIdx.x * 3 + 2] = sh;
    }
  }
  __syncthreads();

  // Decoder out-phase: 16 rows x 4096 cols, wdec register-cached, coalesced f4 stores.
#pragma unroll
  for (int g = 0; g < 4; ++g) {
    const int c4 = g * 1024 + t * 4;
    float wd[4][8];
#pragma unroll
    for (int j = 0; j < 4; ++j) {
      float4 a = *reinterpret_cast<const float4*>(wdec + (size_t)(c4 + j) * 8);
      float4 b = *reinterpret_cast<const float4*>(wdec + (size_t)(c4 + j) * 8 + 4);
      wd[j][0] = a.x; wd[j][1] = a.y; wd[j][2] = a.z; wd[j][3] = a.w;
      wd[j][4] = b.x; wd[j][5] = b.y; wd[j][6] = b.z; wd[j][7] = b.w;
    }
    float4 bd = *reinterpret_cast<const float4*>(bdec + c4);
    for (int r = 0; r < 16; ++r) {
      float4 a0 = *reinterpret_cast<const float4*>(&absL[r * 8]);      // broadcast
      float4 a1 = *reinterpret_cast<const float4*>(&absL[r * 8 + 4]);
      float o0 = bd.x, o1 = bd.y, o2 = bd.z, o3 = bd.w;
      float aq[8] = {a0.x, a0.y, a0.z, a0.w, a1.x, a1.y, a1.z, a1.w};
#pragma unroll
      for (int q = 0; q < 8; ++q) {
        o0 = fmaf(aq[q], wd[0][q], o0);
        o1 = fmaf(aq[q], wd[1][q], o1);
        o2 = fmaf(aq[q], wd[2][q], o2);
        o3 = fmaf(aq[q], wd[3][q], o3);
      }
      *reinterpret_cast<float4*>(out + (size_t)(r0 + r) * DIMN + c4) =
          make_float4(o0, o1, o2, o3);
    }
  }
}

// Finalize metric means (1024 block partials) -> f32 at end of d_out
__global__ void k_final(const float* __restrict__ blocksum,
                        float* __restrict__ out) {
  const int t = threadIdx.x;
  float s0 = 0.f, s1 = 0.f, s2 = 0.f;
  for (int b = t; b < 1024; b += 64) {
    s0 += blocksum[b * 3 + 0];
    s1 += blocksum[b * 3 + 1];
    s2 += blocksum[b * 3 + 2];
  }
#pragma unroll
  for (int off = 32; off > 0; off >>= 1) {
    s0 += __shfl_down(s0, off);
    s1 += __shfl_down(s1, off);
    s2 += __shfl_down(s2, off);
  }
  if (t == 0) {
    out[(size_t)B_TOT * DIMN + 0] = s0 / 16384.f;
    out[(size_t)B_TOT * DIMN + 1] = s1 / 16384.f;
    out[(size_t)B_TOT * DIMN + 2] = s2 / 16384.f;
  }
}

extern "C" void kernel_launch(void* const* d_in, const int* in_sizes, int n_in,
                              void* d_out, int out_size, void* d_ws, size_t ws_size,
                              hipStream_t stream) {
  const float *x = nullptr, *wenc = nullptr, *benc = nullptr, *phase = nullptr,
              *wdec = nullptr, *bdec = nullptr, *dis = nullptr;
  for (int i = 0; i < n_in; i++) {
    switch (in_sizes[i]) {
      case 67108864: x = (const float*)d_in[i]; break;      // 16384*4096
      case 65536:    wenc = (const float*)d_in[i]; break;   // 16*4096
      case 16:       benc = (const float*)d_in[i]; break;
      case 8:        phase = (const float*)d_in[i]; break;
      case 32768:    wdec = (const float*)d_in[i]; break;   // 4096*8
      case 4096:     bdec = (const float*)d_in[i]; break;
      case 3:        dis = (const float*)d_in[i]; break;
      default: break;
    }
  }

  float* bsum = (float*)d_ws;                  // 1024*3 floats
  float* out = (float*)d_out;

  hipLaunchKernelGGL(k_fused, dim3(1024), dim3(256), 0, stream,
                     x, wenc, benc, phase, dis, wdec, bdec, out, bsum);
  hipLaunchKernelGGL(k_final, dim3(1), dim3(64), 0, stream, bsum, out);
}